// Round 1
// baseline (164.288 us; speedup 1.0000x reference)
//
#include <hip/hip_runtime.h>
#include <cstddef>

#define IOU_POS_T 0.6f
#define IOU_NEG_T 0.45f
#define F_EPS 1e-6f
#define F_ALPHA 0.25f
#define F_BETA (1.0f/9.0f)
#define MAXM 64

__device__ __forceinline__ void fp_barrier(float& x) { asm volatile("" : "+v"(x)); }

// ---------------- Pass A: per-GT argmax over anchors (packed-key atomicMax) ----
__global__ void __launch_bounds__(256)
dl_assign_argmax(const float* __restrict__ anchors, const float* __restrict__ gt_boxes,
                 unsigned long long* __restrict__ cells, int N, int M)
{
    const int b = blockIdx.y;
    __shared__ float gmnx[MAXM], gmny[MAXM], gmxx[MAXM], gmxy[MAXM], gar[MAXM];
    const int tid = threadIdx.x;
    if (tid < M) {
        const float* g = gt_boxes + ((size_t)b * M + tid) * 5;
        float cx = g[0], cy = g[1], w = g[2], l = g[3];
        float hw = w * 0.5f, hl = l * 0.5f;
        gmnx[tid] = cx - hw; gmny[tid] = cy - hl;
        gmxx[tid] = cx + hw; gmxy[tid] = cy + hl;
        gar[tid]  = w * l;
    }
    __syncthreads();
    const int i = blockIdx.x * blockDim.x + tid;
    if (i >= N) return;
    const float* a = anchors + (size_t)i * 5;
    float ax = a[0], ay = a[1], aw = a[2], al = a[3];
    float ahw = aw * 0.5f, ahl = al * 0.5f;
    float amnx = ax - ahw, amny = ay - ahl, amxx = ax + ahw, amxy = ay + ahl;
    float area_a = aw * al; fp_barrier(area_a);
    unsigned long long* cellb = cells + (size_t)b * M;
    for (int m = 0; m < M; ++m) {
        float wx = fminf(amxx, gmxx[m]) - fmaxf(amnx, gmnx[m]);
        wx = fmaxf(wx, 0.0f);
        float wy = fminf(amxy, gmxy[m]) - fmaxf(amny, gmny[m]);
        wy = fmaxf(wy, 0.0f);
        float inter = wx * wy; fp_barrier(inter);
        float denom = (area_a + gar[m]) - inter + F_EPS;
        float iou = inter / denom;
        if (iou > 0.0f) {
            // higher iou wins; on equal iou, LOWER anchor index wins (numpy first-occurrence)
            unsigned long long key =
                ((unsigned long long)__float_as_uint(iou) << 32) | (unsigned)(~(unsigned)i);
            atomicMax(cellb + m, key);
        }
    }
}

// ---------------- Pass B: losses ------------------------------------------------
__global__ void __launch_bounds__(256)
dl_loss(const float* __restrict__ cls_logits, const float* __restrict__ box_preds,
        const float* __restrict__ intent_logits, const float* __restrict__ anchors,
        const float* __restrict__ gt_boxes, const int* __restrict__ gt_ints,
        const unsigned long long* __restrict__ cells,
        float* __restrict__ acc, unsigned int* __restrict__ npos_acc,
        int N, int M, int C)
{
    const int b = blockIdx.y;
    __shared__ float gmnx[MAXM], gmny[MAXM], gmxx[MAXM], gmxy[MAXM], gar[MAXM];
    __shared__ float gcx[MAXM], gcy[MAXM], gw[MAXM], gl[MAXM], ga[MAXM];
    __shared__ int gint[MAXM], fidx[MAXM];
    const int tid = threadIdx.x;
    if (tid < M) {
        const float* g = gt_boxes + ((size_t)b * M + tid) * 5;
        float cx = g[0], cy = g[1], w = g[2], l = g[3], ang = g[4];
        float hw = w * 0.5f, hl = l * 0.5f;
        gmnx[tid] = cx - hw; gmny[tid] = cy - hl;
        gmxx[tid] = cx + hw; gmxy[tid] = cy + hl;
        gar[tid]  = w * l;
        gcx[tid] = cx; gcy[tid] = cy; gw[tid] = w; gl[tid] = l; ga[tid] = ang;
        gint[tid] = gt_ints[(size_t)b * M + tid];
        unsigned long long cell = cells[(size_t)b * M + tid];
        float fiou = __uint_as_float((unsigned)(cell >> 32));
        int fi = (int)(~(unsigned)cell);
        fidx[tid] = (fiou >= IOU_NEG_T) ? fi : -1;
    }
    __syncthreads();

    const int i = blockIdx.x * blockDim.x + tid;
    float cls_s = 0.0f, box_s = 0.0f, int_s = 0.0f;
    int np_ = 0;
    if (i < N) {
        const float* a = anchors + (size_t)i * 5;
        float ax = a[0], ay = a[1], aw = a[2], al = a[3], aa = a[4];
        float ahw = aw * 0.5f, ahl = al * 0.5f;
        float amnx = ax - ahw, amny = ay - ahl, amxx = ax + ahw, amxy = ay + ahl;
        float area_a = aw * al; fp_barrier(area_a);
        float bestv = -1.0f; int bestm = 0;
        for (int m = 0; m < M; ++m) {
            float wx = fminf(amxx, gmxx[m]) - fmaxf(amnx, gmnx[m]);
            wx = fmaxf(wx, 0.0f);
            float wy = fminf(amxy, gmxy[m]) - fmaxf(amny, gmny[m]);
            wy = fmaxf(wy, 0.0f);
            float inter = wx * wy; fp_barrier(inter);
            float denom = (area_a + gar[m]) - inter + F_EPS;
            float iou = inter / denom;
            if (iou > bestv) { bestv = iou; bestm = m; }  // strict > keeps first index
        }
        bool forced = false;
        for (int m = 0; m < M; ++m) forced |= (fidx[m] == i);
        const bool pos = (bestv >= IOU_POS_T) || forced;
        const bool neg = bestv < IOU_NEG_T;
        if (pos || neg) {
            float x = cls_logits[(size_t)b * N + i];
            float t = pos ? 1.0f : 0.0f;
            float ce = fmaxf(x, 0.0f) - x * t + log1pf(expf(-fabsf(x)));
            float p = 1.0f / (1.0f + expf(-x));
            float p_t = p * t + (1.0f - p) * (1.0f - t);
            float a_t = F_ALPHA * t + (1.0f - F_ALPHA) * (1.0f - t);
            float om = 1.0f - p_t;
            cls_s = a_t * ce * (om * om);
        }
        if (pos) {
            np_ = 1;
            const int m = bestm;
            float dx = (gcx[m] - ax) / (aw + F_EPS);
            float dy = (gcy[m] - ay) / (al + F_EPS);
            float dwv = logf(gw[m] / (aw + F_EPS) + F_EPS);
            float dlv = logf(gl[m] / (al + F_EPS) + F_EPS);
            float da = ga[m] - aa;
            float tgt6[6] = { dx, dy, dwv, dlv, sinf(da), cosf(da) };
            const float* bp = box_preds + ((size_t)b * N + i) * 6;
            #pragma unroll
            for (int k = 0; k < 6; ++k) {
                float d = fabsf(bp[k] - tgt6[k]);
                box_s += (d < F_BETA) ? (0.5f * d * d / F_BETA) : (d - 0.5f * F_BETA);
            }
            const float* il = intent_logits + ((size_t)b * N + i) * C;
            float mx = il[0];
            for (int c = 1; c < C; ++c) mx = fmaxf(mx, il[c]);
            float se = 0.0f;
            for (int c = 0; c < C; ++c) se += expf(il[c] - mx);
            int tg = gint[m]; tg = tg < 0 ? 0 : (tg > C - 1 ? C - 1 : tg);
            int_s = (mx + logf(se)) - il[tg];
        }
    }

    // block reduction: wave shuffle then cross-wave via LDS
    #pragma unroll
    for (int off = 32; off; off >>= 1) {
        cls_s += __shfl_down(cls_s, off);
        box_s += __shfl_down(box_s, off);
        int_s += __shfl_down(int_s, off);
        np_   += __shfl_down(np_, off);
    }
    __shared__ float r0[4], r1[4], r2[4];
    __shared__ int r3[4];
    const int wave = tid >> 6, lane = tid & 63;
    if (lane == 0) { r0[wave] = cls_s; r1[wave] = box_s; r2[wave] = int_s; r3[wave] = np_; }
    __syncthreads();
    if (tid == 0) {
        float c = r0[0] + r0[1] + r0[2] + r0[3];
        float bx = r1[0] + r1[1] + r1[2] + r1[3];
        float it = r2[0] + r2[1] + r2[2] + r2[3];
        int   n  = r3[0] + r3[1] + r3[2] + r3[3];
        if (c != 0.0f)  atomicAdd(&acc[0], c);
        if (bx != 0.0f) atomicAdd(&acc[1], bx);
        if (it != 0.0f) atomicAdd(&acc[2], it);
        if (n) atomicAdd(npos_acc, (unsigned)n);
    }
}

// ---------------- finalize ------------------------------------------------------
__global__ void dl_finalize(const float* __restrict__ acc, const unsigned int* __restrict__ npos,
                            float* __restrict__ out)
{
    unsigned n = *npos;
    float denom = (float)(n < 1u ? 1u : n);
    float cls = acc[0] / denom;
    float bx  = acc[1] / denom;
    float it  = acc[2] / denom;
    out[0] = 1.0f * cls + 1.0f * bx + 0.5f * it;
    out[1] = cls;
    out[2] = bx;
    out[3] = it;
    out[4] = (float)n;
}

extern "C" void kernel_launch(void* const* d_in, const int* in_sizes, int n_in,
                              void* d_out, int out_size, void* d_ws, size_t ws_size,
                              hipStream_t stream) {
    const float* cls_logits    = (const float*)d_in[0];
    const float* box_preds     = (const float*)d_in[1];
    const float* intent_logits = (const float*)d_in[2];
    const float* anchors       = (const float*)d_in[3];
    const float* gt_boxes      = (const float*)d_in[4];
    const int*   gt_ints       = (const int*)d_in[5];

    const int N = in_sizes[3] / 5;              // anchors [N,5]
    const int B = in_sizes[0] / N;              // cls_logits [B,N,1]
    const int M = in_sizes[5] / B;              // gt_intentions [B,M]
    const int C = in_sizes[2] / in_sizes[0];    // intention_logits [B,N,C]

    unsigned long long* cells = (unsigned long long*)d_ws;
    float* acc = (float*)((char*)d_ws + (size_t)B * M * 8);
    unsigned int* npos = (unsigned int*)((char*)acc + 3 * sizeof(float));
    size_t zbytes = (size_t)B * M * 8 + 4 * sizeof(float);
    hipMemsetAsync(d_ws, 0, zbytes, stream);

    dim3 grid((N + 255) / 256, B);
    dl_assign_argmax<<<grid, 256, 0, stream>>>(anchors, gt_boxes, cells, N, M);
    dl_loss<<<grid, 256, 0, stream>>>(cls_logits, box_preds, intent_logits, anchors,
                                      gt_boxes, gt_ints, cells, acc, npos, N, M, C);
    dl_finalize<<<1, 1, 0, stream>>>(acc, npos, (float*)d_out);
}

// Round 2
// 137.419 us; speedup vs baseline: 1.1955x; 1.1955x over previous
//
#include <hip/hip_runtime.h>
#include <cstddef>

#define IOU_POS_T 0.6f
#define IOU_NEG_T 0.45f
#define F_EPS 1e-6f
#define F_ALPHA 0.25f
#define F_BETA (1.0f/9.0f)
#define MAXM 64
#define BINF 3.402823466e+38f

__device__ __forceinline__ void fp_barrier(float& x) { asm volatile("" : "+v"(x)); }

// ---------------- Pass A: per-GT argmax over anchors (packed-key atomicMax) ----
__global__ void __launch_bounds__(256)
dl_assign_argmax(const float* __restrict__ anchors, const float* __restrict__ gt_boxes,
                 unsigned long long* __restrict__ cells, int N, int M)
{
    const int b = blockIdx.y;
    const int tid = threadIdx.x;
    const int i = blockIdx.x * 256 + tid;
    __shared__ float gmnx[MAXM], gmny[MAXM], gmxx[MAXM], gmxy[MAXM], gar[MAXM];
    __shared__ float wbb[4][4];            // per-wave {mnx, mny, mxx, mxy}
    __shared__ unsigned int smask0, smask1;

    if (tid < M) {
        const float* g = gt_boxes + ((size_t)b * M + tid) * 5;
        float cx = g[0], cy = g[1], w = g[2], l = g[3];
        float hw = w * 0.5f, hl = l * 0.5f;
        gmnx[tid] = cx - hw; gmny[tid] = cy - hl;
        gmxx[tid] = cx + hw; gmxy[tid] = cy + hl;
        gar[tid]  = w * l;
    }
    if (tid == 0) { smask0 = 0; smask1 = 0; }

    const bool act = i < N;
    float amnx = BINF, amny = BINF, amxx = -BINF, amxy = -BINF, area_a = 0.0f;
    if (act) {
        const float* a = anchors + (size_t)i * 5;
        float ax = a[0], ay = a[1], aw = a[2], al = a[3];
        amnx = ax - aw * 0.5f; amny = ay - al * 0.5f;
        amxx = ax + aw * 0.5f; amxy = ay + al * 0.5f;
        area_a = aw * al; fp_barrier(area_a);
    }
    // block bounding box: wave butterfly then cross-wave via LDS
    float r0 = amnx, r1 = amny, r2 = amxx, r3 = amxy;
    #pragma unroll
    for (int off = 32; off; off >>= 1) {
        r0 = fminf(r0, __shfl_xor(r0, off));
        r1 = fminf(r1, __shfl_xor(r1, off));
        r2 = fmaxf(r2, __shfl_xor(r2, off));
        r3 = fmaxf(r3, __shfl_xor(r3, off));
    }
    const int wave = tid >> 6, lane = tid & 63;
    if (lane == 0) { wbb[wave][0] = r0; wbb[wave][1] = r1; wbb[wave][2] = r2; wbb[wave][3] = r3; }
    __syncthreads();
    if (tid < M) {
        float bmnx = fminf(fminf(wbb[0][0], wbb[1][0]), fminf(wbb[2][0], wbb[3][0]));
        float bmny = fminf(fminf(wbb[0][1], wbb[1][1]), fminf(wbb[2][1], wbb[3][1]));
        float bmxx = fmaxf(fmaxf(wbb[0][2], wbb[1][2]), fmaxf(wbb[2][2], wbb[3][2]));
        float bmxy = fmaxf(fmaxf(wbb[0][3], wbb[1][3]), fmaxf(wbb[2][3], wbb[3][3]));
        float wxb = fminf(bmxx, gmxx[tid]) - fmaxf(bmnx, gmnx[tid]);
        float wyb = fminf(bmxy, gmxy[tid]) - fmaxf(bmny, gmny[tid]);
        if (wxb > 0.0f && wyb > 0.0f) {
            if (tid < 32) atomicOr(&smask0, 1u << tid);
            else          atomicOr(&smask1, 1u << (tid - 32));
        }
    }
    __syncthreads();
    unsigned long long mask = (unsigned long long)smask0 | ((unsigned long long)smask1 << 32);
    if (!act) mask = 0;
    unsigned long long* cellb = cells + (size_t)b * M;
    while (mask) {
        const int m = (int)__builtin_ctzll(mask); mask &= mask - 1;
        float wx = fminf(amxx, gmxx[m]) - fmaxf(amnx, gmnx[m]); wx = fmaxf(wx, 0.0f);
        float wy = fminf(amxy, gmxy[m]) - fmaxf(amny, gmny[m]); wy = fmaxf(wy, 0.0f);
        float inter = wx * wy; fp_barrier(inter);
        if (inter > 0.0f) {
            float denom = (area_a + gar[m]) - inter + F_EPS;
            float iou = inter / denom;
            // higher iou wins; on equal iou, LOWER anchor index wins (numpy first-occurrence)
            unsigned long long key =
                ((unsigned long long)__float_as_uint(iou) << 32) | (unsigned)(~(unsigned)i);
            atomicMax(cellb + m, key);
        }
    }
}

// ---------------- Pass B: losses ------------------------------------------------
__global__ void __launch_bounds__(256)
dl_loss(const float* __restrict__ cls_logits, const float* __restrict__ box_preds,
        const float* __restrict__ intent_logits, const float* __restrict__ anchors,
        const float* __restrict__ gt_boxes, const int* __restrict__ gt_ints,
        const unsigned long long* __restrict__ cells,
        float* __restrict__ acc, unsigned int* __restrict__ npos_acc,
        int N, int M, int C)
{
    const int b = blockIdx.y;
    const int tid = threadIdx.x;
    const int ibase = blockIdx.x * 256;
    const int i = ibase + tid;
    __shared__ float gmnx[MAXM], gmny[MAXM], gmxx[MAXM], gmxy[MAXM], gar[MAXM];
    __shared__ float gcx[MAXM], gcy[MAXM], gw[MAXM], gl[MAXM], ga[MAXM];
    __shared__ int gint[MAXM];
    __shared__ float wbb[4][4];
    __shared__ unsigned int smask0, smask1;
    __shared__ unsigned char sforce[256];

    sforce[tid] = 0;
    if (tid < M) {
        const float* g = gt_boxes + ((size_t)b * M + tid) * 5;
        float cx = g[0], cy = g[1], w = g[2], l = g[3], ang = g[4];
        float hw = w * 0.5f, hl = l * 0.5f;
        gmnx[tid] = cx - hw; gmny[tid] = cy - hl;
        gmxx[tid] = cx + hw; gmxy[tid] = cy + hl;
        gar[tid]  = w * l;
        gcx[tid] = cx; gcy[tid] = cy; gw[tid] = w; gl[tid] = l; ga[tid] = ang;
        gint[tid] = gt_ints[(size_t)b * M + tid];
    }
    if (tid == 0) { smask0 = 0; smask1 = 0; }

    const bool act = i < N;
    float ax = 0, ay = 0, aw = 0, al = 0, aa = 0;
    float amnx = BINF, amny = BINF, amxx = -BINF, amxy = -BINF, area_a = 0.0f;
    if (act) {
        const float* a = anchors + (size_t)i * 5;
        ax = a[0]; ay = a[1]; aw = a[2]; al = a[3]; aa = a[4];
        amnx = ax - aw * 0.5f; amny = ay - al * 0.5f;
        amxx = ax + aw * 0.5f; amxy = ay + al * 0.5f;
        area_a = aw * al; fp_barrier(area_a);
    }
    float r0 = amnx, r1 = amny, r2 = amxx, r3 = amxy;
    #pragma unroll
    for (int off = 32; off; off >>= 1) {
        r0 = fminf(r0, __shfl_xor(r0, off));
        r1 = fminf(r1, __shfl_xor(r1, off));
        r2 = fmaxf(r2, __shfl_xor(r2, off));
        r3 = fmaxf(r3, __shfl_xor(r3, off));
    }
    const int wave = tid >> 6, lane = tid & 63;
    if (lane == 0) { wbb[wave][0] = r0; wbb[wave][1] = r1; wbb[wave][2] = r2; wbb[wave][3] = r3; }
    __syncthreads();
    if (tid < M) {
        float bmnx = fminf(fminf(wbb[0][0], wbb[1][0]), fminf(wbb[2][0], wbb[3][0]));
        float bmny = fminf(fminf(wbb[0][1], wbb[1][1]), fminf(wbb[2][1], wbb[3][1]));
        float bmxx = fmaxf(fmaxf(wbb[0][2], wbb[1][2]), fmaxf(wbb[2][2], wbb[3][2]));
        float bmxy = fmaxf(fmaxf(wbb[0][3], wbb[1][3]), fmaxf(wbb[2][3], wbb[3][3]));
        float wxb = fminf(bmxx, gmxx[tid]) - fmaxf(bmnx, gmnx[tid]);
        float wyb = fminf(bmxy, gmxy[tid]) - fmaxf(bmny, gmny[tid]);
        if (wxb > 0.0f && wyb > 0.0f) {
            if (tid < 32) atomicOr(&smask0, 1u << tid);
            else          atomicOr(&smask1, 1u << (tid - 32));
        }
        // forced-positive marking for anchors in this block
        unsigned long long cell = cells[(size_t)b * M + tid];
        float fiou = __uint_as_float((unsigned)(cell >> 32));
        int fi = (int)(~(unsigned)cell);
        if (fiou >= IOU_NEG_T && fi >= ibase && fi < ibase + 256) sforce[fi - ibase] = 1;
    }
    __syncthreads();

    float cls_s = 0.0f, box_s = 0.0f, int_s = 0.0f;
    int np_ = 0;
    if (act) {
        unsigned long long mask = (unsigned long long)smask0 | ((unsigned long long)smask1 << 32);
        float bestv = 0.0f; int bestm = 0;
        while (mask) {
            const int m = (int)__builtin_ctzll(mask); mask &= mask - 1;
            float wx = fminf(amxx, gmxx[m]) - fmaxf(amnx, gmnx[m]); wx = fmaxf(wx, 0.0f);
            float wy = fminf(amxy, gmxy[m]) - fmaxf(amny, gmny[m]); wy = fmaxf(wy, 0.0f);
            float inter = wx * wy; fp_barrier(inter);
            if (inter > 0.0f) {
                float denom = (area_a + gar[m]) - inter + F_EPS;
                float iou = inter / denom;
                if (iou > bestv) { bestv = iou; bestm = m; }  // strict > keeps first index
            }
        }
        const bool forced = sforce[tid] != 0;
        const bool pos = (bestv >= IOU_POS_T) || forced;
        const bool neg = bestv < IOU_NEG_T;
        if (pos || neg) {
            float x = cls_logits[(size_t)b * N + i];
            float t = pos ? 1.0f : 0.0f;
            float ce = fmaxf(x, 0.0f) - x * t + log1pf(expf(-fabsf(x)));
            float p = 1.0f / (1.0f + expf(-x));
            float p_t = p * t + (1.0f - p) * (1.0f - t);
            float a_t = F_ALPHA * t + (1.0f - F_ALPHA) * (1.0f - t);
            float om = 1.0f - p_t;
            cls_s = a_t * ce * (om * om);
        }
        if (pos) {
            np_ = 1;
            const int m = bestm;
            float dx = (gcx[m] - ax) / (aw + F_EPS);
            float dy = (gcy[m] - ay) / (al + F_EPS);
            float dwv = logf(gw[m] / (aw + F_EPS) + F_EPS);
            float dlv = logf(gl[m] / (al + F_EPS) + F_EPS);
            float da = ga[m] - aa;
            float tgt6[6] = { dx, dy, dwv, dlv, sinf(da), cosf(da) };
            const float* bp = box_preds + ((size_t)b * N + i) * 6;
            #pragma unroll
            for (int k = 0; k < 6; ++k) {
                float d = fabsf(bp[k] - tgt6[k]);
                box_s += (d < F_BETA) ? (0.5f * d * d / F_BETA) : (d - 0.5f * F_BETA);
            }
            const float* il = intent_logits + ((size_t)b * N + i) * C;
            float mx = il[0];
            for (int c = 1; c < C; ++c) mx = fmaxf(mx, il[c]);
            float se = 0.0f;
            for (int c = 0; c < C; ++c) se += expf(il[c] - mx);
            int tg = gint[m]; tg = tg < 0 ? 0 : (tg > C - 1 ? C - 1 : tg);
            int_s = (mx + logf(se)) - il[tg];
        }
    }

    // block reduction: wave shuffle then cross-wave via LDS
    #pragma unroll
    for (int off = 32; off; off >>= 1) {
        cls_s += __shfl_down(cls_s, off);
        box_s += __shfl_down(box_s, off);
        int_s += __shfl_down(int_s, off);
        np_   += __shfl_down(np_, off);
    }
    __shared__ float q0[4], q1[4], q2[4];
    __shared__ int q3[4];
    if (lane == 0) { q0[wave] = cls_s; q1[wave] = box_s; q2[wave] = int_s; q3[wave] = np_; }
    __syncthreads();
    if (tid == 0) {
        float c  = q0[0] + q0[1] + q0[2] + q0[3];
        float bx = q1[0] + q1[1] + q1[2] + q1[3];
        float it = q2[0] + q2[1] + q2[2] + q2[3];
        int   n  = q3[0] + q3[1] + q3[2] + q3[3];
        if (c != 0.0f)  atomicAdd(&acc[0], c);
        if (bx != 0.0f) atomicAdd(&acc[1], bx);
        if (it != 0.0f) atomicAdd(&acc[2], it);
        if (n) atomicAdd(npos_acc, (unsigned)n);
    }
}

// ---------------- finalize ------------------------------------------------------
__global__ void dl_finalize(const float* __restrict__ acc, const unsigned int* __restrict__ npos,
                            float* __restrict__ out)
{
    unsigned n = *npos;
    float denom = (float)(n < 1u ? 1u : n);
    float cls = acc[0] / denom;
    float bx  = acc[1] / denom;
    float it  = acc[2] / denom;
    out[0] = 1.0f * cls + 1.0f * bx + 0.5f * it;
    out[1] = cls;
    out[2] = bx;
    out[3] = it;
    out[4] = (float)n;
}

extern "C" void kernel_launch(void* const* d_in, const int* in_sizes, int n_in,
                              void* d_out, int out_size, void* d_ws, size_t ws_size,
                              hipStream_t stream) {
    const float* cls_logits    = (const float*)d_in[0];
    const float* box_preds     = (const float*)d_in[1];
    const float* intent_logits = (const float*)d_in[2];
    const float* anchors       = (const float*)d_in[3];
    const float* gt_boxes      = (const float*)d_in[4];
    const int*   gt_ints       = (const int*)d_in[5];

    const int N = in_sizes[3] / 5;              // anchors [N,5]
    const int B = in_sizes[0] / N;              // cls_logits [B,N,1]
    const int M = in_sizes[5] / B;              // gt_intentions [B,M]
    const int C = in_sizes[2] / in_sizes[0];    // intention_logits [B,N,C]

    unsigned long long* cells = (unsigned long long*)d_ws;
    float* acc = (float*)((char*)d_ws + (size_t)B * M * 8);
    unsigned int* npos = (unsigned int*)((char*)acc + 3 * sizeof(float));
    size_t zbytes = (size_t)B * M * 8 + 4 * sizeof(float);
    hipMemsetAsync(d_ws, 0, zbytes, stream);

    dim3 grid((N + 255) / 256, B);
    dl_assign_argmax<<<grid, 256, 0, stream>>>(anchors, gt_boxes, cells, N, M);
    dl_loss<<<grid, 256, 0, stream>>>(cls_logits, box_preds, intent_logits, anchors,
                                      gt_boxes, gt_ints, cells, acc, npos, N, M, C);
    dl_finalize<<<1, 1, 0, stream>>>(acc, npos, (float*)d_out);
}

// Round 3
// 44.260 us; speedup vs baseline: 3.7119x; 3.1048x over previous
//
#include <hip/hip_runtime.h>
#include <cstddef>

#define IOU_POS_T 0.6f
#define IOU_NEG_T 0.45f
#define F_EPS 1e-6f
#define F_ALPHA 0.25f
#define F_BETA (1.0f/9.0f)
#define MAXM 64
#define BINF 3.402823466e+38f

__device__ __forceinline__ void fp_barrier(float& x) { asm volatile("" : "+v"(x)); }

// ---------------- Pass A: per-GT argmax over anchors ---------------------------
// Block-level LDS atomicMax pre-reduction, then <=M global atomicMax per block.
__global__ void __launch_bounds__(256)
dl_assign(const float* __restrict__ anchors, const float* __restrict__ gt_boxes,
          unsigned long long* __restrict__ cells, float4* __restrict__ bbb,
          int N, int M)
{
    const int b = blockIdx.y;
    const int tid = threadIdx.x;
    const int i = blockIdx.x * 256 + tid;
    __shared__ float gmnx[MAXM], gmny[MAXM], gmxx[MAXM], gmxy[MAXM], gar[MAXM];
    __shared__ unsigned long long lcell[MAXM];
    __shared__ float wbb[4][4];
    __shared__ unsigned long long smask;

    float tmnx = 0, tmny = 0, tmxx = 0, tmxy = 0;   // own GT corners (tid<M)
    if (tid < M) {
        const float* g = gt_boxes + ((size_t)b * M + tid) * 5;
        float cx = g[0], cy = g[1], w = g[2], l = g[3];
        float hw = w * 0.5f, hl = l * 0.5f;
        tmnx = cx - hw; tmny = cy - hl; tmxx = cx + hw; tmxy = cy + hl;
        gmnx[tid] = tmnx; gmny[tid] = tmny; gmxx[tid] = tmxx; gmxy[tid] = tmxy;
        gar[tid] = w * l;
        lcell[tid] = 0ull;
    }
    const bool act = i < N;
    float amnx = BINF, amny = BINF, amxx = -BINF, amxy = -BINF, area_a = 0.0f;
    if (act) {
        const float* a = anchors + (size_t)i * 5;
        float ax = a[0], ay = a[1], aw = a[2], al = a[3];
        amnx = ax - aw * 0.5f; amny = ay - al * 0.5f;
        amxx = ax + aw * 0.5f; amxy = ay + al * 0.5f;
        area_a = aw * al; fp_barrier(area_a);
    }
    // block bounding box: wave butterfly then cross-wave via LDS
    float r0 = amnx, r1 = amny, r2 = amxx, r3 = amxy;
    #pragma unroll
    for (int off = 32; off; off >>= 1) {
        r0 = fminf(r0, __shfl_xor(r0, off));
        r1 = fminf(r1, __shfl_xor(r1, off));
        r2 = fmaxf(r2, __shfl_xor(r2, off));
        r3 = fmaxf(r3, __shfl_xor(r3, off));
    }
    const int wave = tid >> 6;
    if ((tid & 63) == 0) { wbb[wave][0] = r0; wbb[wave][1] = r1; wbb[wave][2] = r2; wbb[wave][3] = r3; }
    __syncthreads();
    if (tid < 64) {   // wave 0 builds the GT shortlist mask via ballot
        float bmnx = fminf(fminf(wbb[0][0], wbb[1][0]), fminf(wbb[2][0], wbb[3][0]));
        float bmny = fminf(fminf(wbb[0][1], wbb[1][1]), fminf(wbb[2][1], wbb[3][1]));
        float bmxx = fmaxf(fmaxf(wbb[0][2], wbb[1][2]), fmaxf(wbb[2][2], wbb[3][2]));
        float bmxy = fmaxf(fmaxf(wbb[0][3], wbb[1][3]), fmaxf(wbb[2][3], wbb[3][3]));
        bool ov = false;
        if (tid < M) {
            float wxb = fminf(bmxx, tmxx) - fmaxf(bmnx, tmnx);
            float wyb = fminf(bmxy, tmxy) - fmaxf(bmny, tmny);
            ov = (wxb > 0.0f) && (wyb > 0.0f);
        }
        unsigned long long bal = __ballot(ov);
        if (tid == 0) {
            smask = bal;
            if (b == 0) bbb[blockIdx.x] = make_float4(bmnx, bmny, bmxx, bmxy);
        }
    }
    __syncthreads();
    unsigned long long mask = act ? smask : 0ull;
    while (mask) {
        const int m = (int)__builtin_ctzll(mask); mask &= mask - 1;
        float wx = fminf(amxx, gmxx[m]) - fmaxf(amnx, gmnx[m]); wx = fmaxf(wx, 0.0f);
        float wy = fminf(amxy, gmxy[m]) - fmaxf(amny, gmny[m]); wy = fmaxf(wy, 0.0f);
        float inter = wx * wy; fp_barrier(inter);
        if (inter > 0.0f) {
            float denom = (area_a + gar[m]) - inter + F_EPS;
            float iou = inter / denom;
            // higher iou wins; equal iou -> LOWER anchor index (numpy first-occurrence)
            unsigned long long key =
                ((unsigned long long)__float_as_uint(iou) << 32) | (unsigned)(~(unsigned)i);
            atomicMax(&lcell[m], key);
        }
    }
    __syncthreads();
    if (tid < M) {
        unsigned long long v = lcell[tid];
        if (v) atomicMax(cells + (size_t)b * M + tid, v);
    }
}

// ---------------- Pass B: losses (no global atomics; per-block partials) -------
__global__ void __launch_bounds__(256)
dl_loss(const float* __restrict__ cls_logits, const float* __restrict__ box_preds,
        const float* __restrict__ intent_logits, const float* __restrict__ anchors,
        const float* __restrict__ gt_boxes, const int* __restrict__ gt_ints,
        const unsigned long long* __restrict__ cells, const float4* __restrict__ bbb,
        float4* __restrict__ parts, int N, int M, int C)
{
    const int b = blockIdx.y;
    const int tid = threadIdx.x;
    const int ibase = blockIdx.x * 256;
    const int i = ibase + tid;
    __shared__ float gmnx[MAXM], gmny[MAXM], gmxx[MAXM], gmxy[MAXM], gar[MAXM];
    __shared__ float gcx[MAXM], gcy[MAXM], gw[MAXM], gl[MAXM], ga[MAXM];
    __shared__ int gint[MAXM];
    __shared__ unsigned long long smask;
    __shared__ unsigned char sforce[256];

    sforce[tid] = 0;
    float tmnx = 0, tmny = 0, tmxx = 0, tmxy = 0;
    unsigned long long mycell = 0;
    if (tid < M) {
        const float* g = gt_boxes + ((size_t)b * M + tid) * 5;
        float cx = g[0], cy = g[1], w = g[2], l = g[3], ang = g[4];
        float hw = w * 0.5f, hl = l * 0.5f;
        tmnx = cx - hw; tmny = cy - hl; tmxx = cx + hw; tmxy = cy + hl;
        gmnx[tid] = tmnx; gmny[tid] = tmny; gmxx[tid] = tmxx; gmxy[tid] = tmxy;
        gar[tid]  = w * l;
        gcx[tid] = cx; gcy[tid] = cy; gw[tid] = w; gl[tid] = l; ga[tid] = ang;
        gint[tid] = gt_ints[(size_t)b * M + tid];
        mycell = cells[(size_t)b * M + tid];
    }
    const bool act = i < N;
    float ax = 0, ay = 0, aw = 0, al = 0, aa = 0;
    float amnx = 0, amny = 0, amxx = 0, amxy = 0, area_a = 0.0f;
    if (act) {
        const float* a = anchors + (size_t)i * 5;
        ax = a[0]; ay = a[1]; aw = a[2]; al = a[3]; aa = a[4];
        amnx = ax - aw * 0.5f; amny = ay - al * 0.5f;
        amxx = ax + aw * 0.5f; amxy = ay + al * 0.5f;
        area_a = aw * al; fp_barrier(area_a);
    }
    __syncthreads();   // sforce zeroing + gt smem visible before wave-0 marking
    if (tid < 64) {
        bool ov = false;
        if (tid < M) {
            float4 bb = bbb[blockIdx.x];
            float wxb = fminf(bb.z, tmxx) - fmaxf(bb.x, tmnx);
            float wyb = fminf(bb.w, tmxy) - fmaxf(bb.y, tmny);
            ov = (wxb > 0.0f) && (wyb > 0.0f);
        }
        unsigned long long bal = __ballot(ov);
        if (tid == 0) smask = bal;
    }
    if (tid < M) {   // forced-positive marking for anchors in this block
        float fiou = __uint_as_float((unsigned)(mycell >> 32));
        int fi = (int)(~(unsigned)mycell);
        if (fiou >= IOU_NEG_T && fi >= ibase && fi < ibase + 256) sforce[fi - ibase] = 1;
    }
    __syncthreads();

    float cls_s = 0.0f, box_s = 0.0f, int_s = 0.0f, np_ = 0.0f;
    if (act) {
        unsigned long long mask = smask;
        float bestv = 0.0f; int bestm = 0;
        while (mask) {
            const int m = (int)__builtin_ctzll(mask); mask &= mask - 1;
            float wx = fminf(amxx, gmxx[m]) - fmaxf(amnx, gmnx[m]); wx = fmaxf(wx, 0.0f);
            float wy = fminf(amxy, gmxy[m]) - fmaxf(amny, gmny[m]); wy = fmaxf(wy, 0.0f);
            float inter = wx * wy; fp_barrier(inter);
            if (inter > 0.0f) {
                float denom = (area_a + gar[m]) - inter + F_EPS;
                float iou = inter / denom;
                if (iou > bestv) { bestv = iou; bestm = m; }  // strict > keeps first index
            }
        }
        const bool forced = sforce[tid] != 0;
        const bool pos = (bestv >= IOU_POS_T) || forced;
        const bool neg = bestv < IOU_NEG_T;
        if (pos || neg) {
            float x = cls_logits[(size_t)b * N + i];
            float t = pos ? 1.0f : 0.0f;
            float ce = fmaxf(x, 0.0f) - x * t + log1pf(expf(-fabsf(x)));
            float p = 1.0f / (1.0f + expf(-x));
            float p_t = p * t + (1.0f - p) * (1.0f - t);
            float a_t = F_ALPHA * t + (1.0f - F_ALPHA) * (1.0f - t);
            float om = 1.0f - p_t;
            cls_s = a_t * ce * (om * om);
        }
        if (pos) {
            np_ = 1.0f;
            const int m = bestm;
            float dx = (gcx[m] - ax) / (aw + F_EPS);
            float dy = (gcy[m] - ay) / (al + F_EPS);
            float dwv = logf(gw[m] / (aw + F_EPS) + F_EPS);
            float dlv = logf(gl[m] / (al + F_EPS) + F_EPS);
            float da = ga[m] - aa;
            float tgt6[6] = { dx, dy, dwv, dlv, sinf(da), cosf(da) };
            const float* bp = box_preds + ((size_t)b * N + i) * 6;
            #pragma unroll
            for (int k = 0; k < 6; ++k) {
                float d = fabsf(bp[k] - tgt6[k]);
                box_s += (d < F_BETA) ? (0.5f * d * d / F_BETA) : (d - 0.5f * F_BETA);
            }
            const float* il = intent_logits + ((size_t)b * N + i) * C;
            float mx = il[0];
            for (int c = 1; c < C; ++c) mx = fmaxf(mx, il[c]);
            float se = 0.0f;
            for (int c = 0; c < C; ++c) se += expf(il[c] - mx);
            int tg = gint[m]; tg = tg < 0 ? 0 : (tg > C - 1 ? C - 1 : tg);
            int_s = (mx + logf(se)) - il[tg];
        }
    }

    // block reduction: wave shuffle then cross-wave via LDS; single float4 store
    #pragma unroll
    for (int off = 32; off; off >>= 1) {
        cls_s += __shfl_down(cls_s, off);
        box_s += __shfl_down(box_s, off);
        int_s += __shfl_down(int_s, off);
        np_   += __shfl_down(np_, off);
    }
    __shared__ float q0[4], q1[4], q2[4], q3[4];
    const int wave = tid >> 6;
    if ((tid & 63) == 0) { q0[wave] = cls_s; q1[wave] = box_s; q2[wave] = int_s; q3[wave] = np_; }
    __syncthreads();
    if (tid == 0) {
        parts[(size_t)b * gridDim.x + blockIdx.x] =
            make_float4(q0[0] + q0[1] + q0[2] + q0[3],
                        q1[0] + q1[1] + q1[2] + q1[3],
                        q2[0] + q2[1] + q2[2] + q2[3],
                        q3[0] + q3[1] + q3[2] + q3[3]);
    }
}

// ---------------- reduce + finalize --------------------------------------------
__global__ void __launch_bounds__(256)
dl_reduce(const float4* __restrict__ parts, int total, float* __restrict__ out)
{
    const int tid = threadIdx.x;
    float c = 0, bx = 0, it = 0, np = 0;
    for (int k = tid; k < total; k += 256) {
        float4 v = parts[k];
        c += v.x; bx += v.y; it += v.z; np += v.w;
    }
    #pragma unroll
    for (int off = 32; off; off >>= 1) {
        c  += __shfl_down(c, off);
        bx += __shfl_down(bx, off);
        it += __shfl_down(it, off);
        np += __shfl_down(np, off);
    }
    __shared__ float q0[4], q1[4], q2[4], q3[4];
    const int wave = tid >> 6;
    if ((tid & 63) == 0) { q0[wave] = c; q1[wave] = bx; q2[wave] = it; q3[wave] = np; }
    __syncthreads();
    if (tid == 0) {
        float cs = q0[0] + q0[1] + q0[2] + q0[3];
        float bs = q1[0] + q1[1] + q1[2] + q1[3];
        float is = q2[0] + q2[1] + q2[2] + q2[3];
        float ns = q3[0] + q3[1] + q3[2] + q3[3];
        float denom = fmaxf(1.0f, ns);
        float cls = cs / denom, bo = bs / denom, in_ = is / denom;
        out[0] = cls + bo + 0.5f * in_;
        out[1] = cls;
        out[2] = bo;
        out[3] = in_;
        out[4] = ns;
    }
}

extern "C" void kernel_launch(void* const* d_in, const int* in_sizes, int n_in,
                              void* d_out, int out_size, void* d_ws, size_t ws_size,
                              hipStream_t stream) {
    const float* cls_logits    = (const float*)d_in[0];
    const float* box_preds     = (const float*)d_in[1];
    const float* intent_logits = (const float*)d_in[2];
    const float* anchors       = (const float*)d_in[3];
    const float* gt_boxes      = (const float*)d_in[4];
    const int*   gt_ints       = (const int*)d_in[5];

    const int N = in_sizes[3] / 5;              // anchors [N,5]
    const int B = in_sizes[0] / N;              // cls_logits [B,N,1]
    const int M = in_sizes[5] / B;              // gt_intentions [B,M]
    const int C = in_sizes[2] / in_sizes[0];    // intention_logits [B,N,C]
    const int nblkx = (N + 255) / 256;

    char* ws = (char*)d_ws;
    unsigned long long* cells = (unsigned long long*)ws;           // B*M*8
    size_t off = ((size_t)B * M * 8 + 255) & ~(size_t)255;
    float4* bbb = (float4*)(ws + off);                              // nblkx*16
    off = (off + (size_t)nblkx * 16 + 255) & ~(size_t)255;
    float4* parts = (float4*)(ws + off);                            // nblkx*B*16

    hipMemsetAsync(cells, 0, (size_t)B * M * 8, stream);

    dim3 grid(nblkx, B);
    dl_assign<<<grid, 256, 0, stream>>>(anchors, gt_boxes, cells, bbb, N, M);
    dl_loss<<<grid, 256, 0, stream>>>(cls_logits, box_preds, intent_logits, anchors,
                                      gt_boxes, gt_ints, cells, bbb, parts, N, M, C);
    dl_reduce<<<1, 256, 0, stream>>>(parts, nblkx * B, (float*)d_out);
}

// Round 4
// 36.781 us; speedup vs baseline: 4.4667x; 1.2034x over previous
//
#include <hip/hip_runtime.h>
#include <cstddef>

#define IOU_POS_T 0.6f
#define IOU_NEG_T 0.45f
#define F_EPS 1e-6f
#define F_ALPHA 0.25f
#define F_BETA (1.0f/9.0f)
#define MAXM 64
#define BINF 3.402823466e+38f

__device__ __forceinline__ void fp_barrier(float& x) { asm volatile("" : "+v"(x)); }

// ---------------- kernel 0: per-block anchor bbox (+ zero cells) ---------------
__global__ void __launch_bounds__(256)
dl_bbox(const float* __restrict__ anchors, float4* __restrict__ bbb,
        unsigned long long* __restrict__ cells, int N, int ncells)
{
    const int tid = threadIdx.x;
    const int i = blockIdx.x * 256 + tid;
    if (blockIdx.x == 0) {
        for (int k = tid; k < ncells; k += 256) cells[k] = 0ull;
    }
    float amnx = BINF, amny = BINF, amxx = -BINF, amxy = -BINF;
    if (i < N) {
        const float* a = anchors + (size_t)i * 5;
        float ax = a[0], ay = a[1], aw = a[2], al = a[3];
        amnx = ax - aw * 0.5f; amny = ay - al * 0.5f;
        amxx = ax + aw * 0.5f; amxy = ay + al * 0.5f;
    }
    #pragma unroll
    for (int off = 32; off; off >>= 1) {
        amnx = fminf(amnx, __shfl_xor(amnx, off));
        amny = fminf(amny, __shfl_xor(amny, off));
        amxx = fmaxf(amxx, __shfl_xor(amxx, off));
        amxy = fmaxf(amxy, __shfl_xor(amxy, off));
    }
    __shared__ float wbb[4][4];
    const int wave = tid >> 6;
    if ((tid & 63) == 0) { wbb[wave][0] = amnx; wbb[wave][1] = amny; wbb[wave][2] = amxx; wbb[wave][3] = amxy; }
    __syncthreads();
    if (tid == 0) {
        float bmnx = fminf(fminf(wbb[0][0], wbb[1][0]), fminf(wbb[2][0], wbb[3][0]));
        float bmny = fminf(fminf(wbb[0][1], wbb[1][1]), fminf(wbb[2][1], wbb[3][1]));
        float bmxx = fmaxf(fmaxf(wbb[0][2], wbb[1][2]), fmaxf(wbb[2][2], wbb[3][2]));
        float bmxy = fmaxf(fmaxf(wbb[0][3], wbb[1][3]), fmaxf(wbb[2][3], wbb[3][3]));
        bbb[blockIdx.x] = make_float4(bmnx, bmny, bmxx, bmxy);
    }
}

// ---------------- Pass A: per-GT argmax over anchors ---------------------------
// Ballot vs precomputed block bbox -> store mask; empty blocks exit immediately.
__global__ void __launch_bounds__(256)
dl_assign(const float* __restrict__ anchors, const float* __restrict__ gt_boxes,
          const float4* __restrict__ bbb, unsigned long long* __restrict__ masks,
          unsigned long long* __restrict__ cells, int N, int M, int nblkx)
{
    const int b = blockIdx.y;
    const int tid = threadIdx.x;
    const int blk = blockIdx.x;
    const int i = blk * 256 + tid;
    __shared__ float gmnx[MAXM], gmny[MAXM], gmxx[MAXM], gmxy[MAXM], gar[MAXM];
    __shared__ unsigned long long lcell[MAXM];
    __shared__ unsigned long long smask_s;

    if (tid < 64) {   // wave 0: build GT shortlist mask vs block bbox
        bool ov = false;
        if (tid < M) {
            const float* g = gt_boxes + ((size_t)b * M + tid) * 5;
            float cx = g[0], cy = g[1], w = g[2], l = g[3];
            float hw = w * 0.5f, hl = l * 0.5f;
            float4 bb = bbb[blk];
            float wxb = fminf(bb.z, cx + hw) - fmaxf(bb.x, cx - hw);
            float wyb = fminf(bb.w, cy + hl) - fmaxf(bb.y, cy - hl);
            ov = (wxb > 0.0f) && (wyb > 0.0f);
        }
        unsigned long long bal = __ballot(ov);
        if (tid == 0) { smask_s = bal; masks[(size_t)b * nblkx + blk] = bal; }
    }
    __syncthreads();
    const unsigned long long sm = smask_s;
    if (sm == 0ull) return;                      // ~75% of blocks leave here

    if (tid < M) {
        const float* g = gt_boxes + ((size_t)b * M + tid) * 5;
        float cx = g[0], cy = g[1], w = g[2], l = g[3];
        float hw = w * 0.5f, hl = l * 0.5f;
        gmnx[tid] = cx - hw; gmny[tid] = cy - hl;
        gmxx[tid] = cx + hw; gmxy[tid] = cy + hl;
        gar[tid] = w * l;
        lcell[tid] = 0ull;
    }
    const bool act = i < N;
    float amnx = 0, amny = 0, amxx = 0, amxy = 0, area_a = 0.0f;
    if (act) {
        const float* a = anchors + (size_t)i * 5;
        float ax = a[0], ay = a[1], aw = a[2], al = a[3];
        amnx = ax - aw * 0.5f; amny = ay - al * 0.5f;
        amxx = ax + aw * 0.5f; amxy = ay + al * 0.5f;
        area_a = aw * al; fp_barrier(area_a);
    }
    __syncthreads();
    unsigned long long mask = act ? sm : 0ull;
    while (mask) {
        const int m = (int)__builtin_ctzll(mask); mask &= mask - 1;
        float wx = fminf(amxx, gmxx[m]) - fmaxf(amnx, gmnx[m]); wx = fmaxf(wx, 0.0f);
        float wy = fminf(amxy, gmxy[m]) - fmaxf(amny, gmny[m]); wy = fmaxf(wy, 0.0f);
        float inter = wx * wy; fp_barrier(inter);
        if (inter > 0.0f) {
            float denom = (area_a + gar[m]) - inter + F_EPS;
            float iou = inter / denom;
            // higher iou wins; equal iou -> LOWER anchor index (numpy first-occurrence)
            unsigned long long key =
                ((unsigned long long)__float_as_uint(iou) << 32) | (unsigned)(~(unsigned)i);
            atomicMax(&lcell[m], key);
        }
    }
    __syncthreads();
    if (tid < M) {
        unsigned long long v = lcell[tid];
        if (v) atomicMax(cells + (size_t)b * M + tid, v);
    }
}

// ---------------- Pass B: losses ----------------------------------------------
__global__ void __launch_bounds__(256)
dl_loss(const float* __restrict__ cls_logits, const float* __restrict__ box_preds,
        const float* __restrict__ intent_logits, const float* __restrict__ anchors,
        const float* __restrict__ gt_boxes, const int* __restrict__ gt_ints,
        const unsigned long long* __restrict__ cells,
        const unsigned long long* __restrict__ masks,
        float4* __restrict__ parts, int N, int M, int C, int nblkx)
{
    const int b = blockIdx.y;
    const int tid = threadIdx.x;
    const int blk = blockIdx.x;
    const int ibase = blk * 256;
    const int i = ibase + tid;
    const int wave = tid >> 6;
    const unsigned long long sm = masks[(size_t)b * nblkx + blk];
    const bool act = i < N;

    if (sm == 0ull) {
        // pure-negative block: focal only, single-value reduction, no anchor reads
        float cls_s = 0.0f;
        if (act) {
            float x = cls_logits[(size_t)b * N + i];
            float ce = fmaxf(x, 0.0f) + log1pf(expf(-fabsf(x)));
            float p = 1.0f / (1.0f + expf(-x));
            float om = p;                        // 1 - p_t with t=0 -> p
            cls_s = (1.0f - F_ALPHA) * ce * (om * om);
        }
        #pragma unroll
        for (int off = 32; off; off >>= 1) cls_s += __shfl_down(cls_s, off);
        __shared__ float q[4];
        if ((tid & 63) == 0) q[wave] = cls_s;
        __syncthreads();
        if (tid == 0)
            parts[(size_t)b * nblkx + blk] = make_float4(q[0] + q[1] + q[2] + q[3], 0.f, 0.f, 0.f);
        return;
    }

    __shared__ float gmnx[MAXM], gmny[MAXM], gmxx[MAXM], gmxy[MAXM], gar[MAXM];
    __shared__ float gcx[MAXM], gcy[MAXM], gw[MAXM], gl[MAXM], ga[MAXM];
    __shared__ int gint[MAXM];
    __shared__ unsigned char sforce[256];

    sforce[tid] = 0;
    unsigned long long mycell = 0;
    if (tid < M) {
        const float* g = gt_boxes + ((size_t)b * M + tid) * 5;
        float cx = g[0], cy = g[1], w = g[2], l = g[3], ang = g[4];
        float hw = w * 0.5f, hl = l * 0.5f;
        gmnx[tid] = cx - hw; gmny[tid] = cy - hl;
        gmxx[tid] = cx + hw; gmxy[tid] = cy + hl;
        gar[tid]  = w * l;
        gcx[tid] = cx; gcy[tid] = cy; gw[tid] = w; gl[tid] = l; ga[tid] = ang;
        gint[tid] = gt_ints[(size_t)b * M + tid];
        mycell = cells[(size_t)b * M + tid];
    }
    float ax = 0, ay = 0, aw = 0, al = 0, aa = 0;
    float amnx = 0, amny = 0, amxx = 0, amxy = 0, area_a = 0.0f;
    if (act) {
        const float* a = anchors + (size_t)i * 5;
        ax = a[0]; ay = a[1]; aw = a[2]; al = a[3]; aa = a[4];
        amnx = ax - aw * 0.5f; amny = ay - al * 0.5f;
        amxx = ax + aw * 0.5f; amxy = ay + al * 0.5f;
        area_a = aw * al; fp_barrier(area_a);
    }
    __syncthreads();   // sforce zeroing visible before marking
    if (tid < M) {     // forced-positive marking for anchors in this block
        float fiou = __uint_as_float((unsigned)(mycell >> 32));
        int fi = (int)(~(unsigned)mycell);
        if (fiou >= IOU_NEG_T && fi >= ibase && fi < ibase + 256) sforce[fi - ibase] = 1;
    }
    __syncthreads();

    float cls_s = 0.0f, box_s = 0.0f, int_s = 0.0f, np_ = 0.0f;
    if (act) {
        unsigned long long mask = sm;
        float bestv = 0.0f; int bestm = 0;
        while (mask) {
            const int m = (int)__builtin_ctzll(mask); mask &= mask - 1;
            float wx = fminf(amxx, gmxx[m]) - fmaxf(amnx, gmnx[m]); wx = fmaxf(wx, 0.0f);
            float wy = fminf(amxy, gmxy[m]) - fmaxf(amny, gmny[m]); wy = fmaxf(wy, 0.0f);
            float inter = wx * wy; fp_barrier(inter);
            if (inter > 0.0f) {
                float denom = (area_a + gar[m]) - inter + F_EPS;
                float iou = inter / denom;
                if (iou > bestv) { bestv = iou; bestm = m; }  // strict > keeps first index
            }
        }
        const bool forced = sforce[tid] != 0;
        const bool pos = (bestv >= IOU_POS_T) || forced;
        const bool neg = bestv < IOU_NEG_T;
        if (pos || neg) {
            float x = cls_logits[(size_t)b * N + i];
            float t = pos ? 1.0f : 0.0f;
            float ce = fmaxf(x, 0.0f) - x * t + log1pf(expf(-fabsf(x)));
            float p = 1.0f / (1.0f + expf(-x));
            float p_t = p * t + (1.0f - p) * (1.0f - t);
            float a_t = F_ALPHA * t + (1.0f - F_ALPHA) * (1.0f - t);
            float om = 1.0f - p_t;
            cls_s = a_t * ce * (om * om);
        }
        if (pos) {
            np_ = 1.0f;
            const int m = bestm;
            float dx = (gcx[m] - ax) / (aw + F_EPS);
            float dy = (gcy[m] - ay) / (al + F_EPS);
            float dwv = logf(gw[m] / (aw + F_EPS) + F_EPS);
            float dlv = logf(gl[m] / (al + F_EPS) + F_EPS);
            float da = ga[m] - aa;
            float tgt6[6] = { dx, dy, dwv, dlv, sinf(da), cosf(da) };
            const float* bp = box_preds + ((size_t)b * N + i) * 6;
            #pragma unroll
            for (int k = 0; k < 6; ++k) {
                float d = fabsf(bp[k] - tgt6[k]);
                box_s += (d < F_BETA) ? (0.5f * d * d / F_BETA) : (d - 0.5f * F_BETA);
            }
            const float* il = intent_logits + ((size_t)b * N + i) * C;
            float mx = il[0];
            for (int c = 1; c < C; ++c) mx = fmaxf(mx, il[c]);
            float se = 0.0f;
            for (int c = 0; c < C; ++c) se += expf(il[c] - mx);
            int tg = gint[m]; tg = tg < 0 ? 0 : (tg > C - 1 ? C - 1 : tg);
            int_s = (mx + logf(se)) - il[tg];
        }
    }

    #pragma unroll
    for (int off = 32; off; off >>= 1) {
        cls_s += __shfl_down(cls_s, off);
        box_s += __shfl_down(box_s, off);
        int_s += __shfl_down(int_s, off);
        np_   += __shfl_down(np_, off);
    }
    __shared__ float q0[4], q1[4], q2[4], q3[4];
    if ((tid & 63) == 0) { q0[wave] = cls_s; q1[wave] = box_s; q2[wave] = int_s; q3[wave] = np_; }
    __syncthreads();
    if (tid == 0) {
        parts[(size_t)b * nblkx + blk] =
            make_float4(q0[0] + q0[1] + q0[2] + q0[3],
                        q1[0] + q1[1] + q1[2] + q1[3],
                        q2[0] + q2[1] + q2[2] + q2[3],
                        q3[0] + q3[1] + q3[2] + q3[3]);
    }
}

// ---------------- reduce + finalize --------------------------------------------
__global__ void __launch_bounds__(256)
dl_reduce(const float4* __restrict__ parts, int total, float* __restrict__ out)
{
    const int tid = threadIdx.x;
    float c = 0, bx = 0, it = 0, np = 0;
    for (int k = tid; k < total; k += 256) {
        float4 v = parts[k];
        c += v.x; bx += v.y; it += v.z; np += v.w;
    }
    #pragma unroll
    for (int off = 32; off; off >>= 1) {
        c  += __shfl_down(c, off);
        bx += __shfl_down(bx, off);
        it += __shfl_down(it, off);
        np += __shfl_down(np, off);
    }
    __shared__ float q0[4], q1[4], q2[4], q3[4];
    const int wave = tid >> 6;
    if ((tid & 63) == 0) { q0[wave] = c; q1[wave] = bx; q2[wave] = it; q3[wave] = np; }
    __syncthreads();
    if (tid == 0) {
        float cs = q0[0] + q0[1] + q0[2] + q0[3];
        float bs = q1[0] + q1[1] + q1[2] + q1[3];
        float is = q2[0] + q2[1] + q2[2] + q2[3];
        float ns = q3[0] + q3[1] + q3[2] + q3[3];
        float denom = fmaxf(1.0f, ns);
        float cls = cs / denom, bo = bs / denom, in_ = is / denom;
        out[0] = cls + bo + 0.5f * in_;
        out[1] = cls;
        out[2] = bo;
        out[3] = in_;
        out[4] = ns;
    }
}

extern "C" void kernel_launch(void* const* d_in, const int* in_sizes, int n_in,
                              void* d_out, int out_size, void* d_ws, size_t ws_size,
                              hipStream_t stream) {
    const float* cls_logits    = (const float*)d_in[0];
    const float* box_preds     = (const float*)d_in[1];
    const float* intent_logits = (const float*)d_in[2];
    const float* anchors       = (const float*)d_in[3];
    const float* gt_boxes     = (const float*)d_in[4];
    const int*   gt_ints       = (const int*)d_in[5];

    const int N = in_sizes[3] / 5;              // anchors [N,5]
    const int B = in_sizes[0] / N;              // cls_logits [B,N,1]
    const int M = in_sizes[5] / B;              // gt_intentions [B,M]
    const int C = in_sizes[2] / in_sizes[0];    // intention_logits [B,N,C]
    const int nblkx = (N + 255) / 256;

    char* ws = (char*)d_ws;
    unsigned long long* cells = (unsigned long long*)ws;            // B*M*8
    size_t off = ((size_t)B * M * 8 + 255) & ~(size_t)255;
    float4* bbb = (float4*)(ws + off);                               // nblkx*16
    off = (off + (size_t)nblkx * 16 + 255) & ~(size_t)255;
    unsigned long long* masks = (unsigned long long*)(ws + off);     // B*nblkx*8
    off = (off + (size_t)B * nblkx * 8 + 255) & ~(size_t)255;
    float4* parts = (float4*)(ws + off);                             // B*nblkx*16

    dim3 grid(nblkx, B);
    dl_bbox<<<nblkx, 256, 0, stream>>>(anchors, bbb, cells, N, B * M);
    dl_assign<<<grid, 256, 0, stream>>>(anchors, gt_boxes, bbb, masks, cells, N, M, nblkx);
    dl_loss<<<grid, 256, 0, stream>>>(cls_logits, box_preds, intent_logits, anchors,
                                      gt_boxes, gt_ints, cells, masks, parts, N, M, C, nblkx);
    dl_reduce<<<1, 256, 0, stream>>>(parts, nblkx * B, (float*)d_out);
}